// Round 7
// baseline (278.718 us; speedup 1.0000x reference)
//
#include <hip/hip_runtime.h>
#include <hip/hip_bf16.h>

// Problem constants
#define BB   4096
#define INW  1024
#define HH   1024
#define KIN  2048      // IN + H
#define NG   5120      // 3H + 2H
#define KH   32        // inner hidden

typedef __bf16 bf16;
typedef __bf16 bf16x4 __attribute__((ext_vector_type(4)));
typedef __bf16 bf16x8 __attribute__((ext_vector_type(8)));
typedef float  floatx4 __attribute__((ext_vector_type(4)));

// ---------------------------------------------------------------------------
// 1. prep: build BOTH GEMM operands in MFMA fragment order (bf16).
//    A (comb = x|h concat):  chunk o = [mt][kk][lane] holds
//      A[m = mt*16 + (lane&15)][k = kk*32 + (lane>>4)*8 .. +7]
//    B (Wg|Wc):              chunk o = [nt][kk][f][lane] holds
//      B[n = nt*128 + f*16 + (lane&15)][k = kk*32 + (lane>>4)*8 .. +7]
//    Both give the GEMM perfectly coalesced base + lane*16B fragment loads.
// ---------------------------------------------------------------------------
#define NA8  (BB * KIN / 8)        // 16B chunks for Ab  (1,048,576)
#define NW8  (NG * KIN / 8)        // 16B chunks for Wb  (1,310,720)

__global__ __launch_bounds__(256) void prep(
    const float* __restrict__ x, const float* __restrict__ h,
    const float* __restrict__ Wg, const float* __restrict__ Wc,
    bf16* __restrict__ Ab, bf16* __restrict__ Wb) {
  int i = blockIdx.x * 256 + threadIdx.x;
  if (i < NA8) {                       // ---- A: concat + cast + frag shuffle
    int lane = i & 63;
    int kk   = (i >> 6) & 63;
    int mt   = i >> 12;
    int m = mt * 16 + (lane & 15);
    int k = kk * 32 + (lane >> 4) * 8;
    const float* src = (k < INW) ? (x + (size_t)m * INW + k)
                                 : (h + (size_t)m * HH + (k - INW));
    float4 v0 = *(const float4*)src;
    float4 v1 = *(const float4*)(src + 4);
    bf16x8 ov;
    ov[0] = (bf16)v0.x; ov[1] = (bf16)v0.y; ov[2] = (bf16)v0.z; ov[3] = (bf16)v0.w;
    ov[4] = (bf16)v1.x; ov[5] = (bf16)v1.y; ov[6] = (bf16)v1.z; ov[7] = (bf16)v1.w;
    *(bf16x8*)(Ab + (size_t)i * 8) = ov;
  } else {                             // ---- B: cast + frag shuffle ----
    int o = i - NA8;
    if (o < NW8) {
      int lane = o & 63;
      int f    = (o >> 6) & 7;
      int kk   = (o >> 9) & 63;
      int nt   = o >> 15;
      int n = nt * 128 + f * 16 + (lane & 15);
      int k = kk * 32 + (lane >> 4) * 8;
      const float* src = (n < 3 * HH) ? (Wg + (size_t)n * KIN + k)
                                      : (Wc + (size_t)(n - 3 * HH) * KIN + k);
      float4 v0 = *(const float4*)src;
      float4 v1 = *(const float4*)(src + 4);
      bf16x8 ov;
      ov[0] = (bf16)v0.x; ov[1] = (bf16)v0.y; ov[2] = (bf16)v0.z; ov[3] = (bf16)v0.w;
      ov[4] = (bf16)v1.x; ov[5] = (bf16)v1.y; ov[6] = (bf16)v1.z; ov[7] = (bf16)v1.w;
      *(bf16x8*)(Wb + (size_t)o * 8) = ov;
    }
  }
}

// ---------------------------------------------------------------------------
// 2. GEMM: G[M,N] = A[M,K] * B[N,K]^T, BOTH operands pre-shuffled to MFMA
//    fragment order. R7: NO LDS, NO BARRIERS — the structural ~20% vmcnt(0)
//    barrier-drain of the staged structure is gone. Pure K-loop of coalesced
//    global fragment loads + MFMA, register double-buffered (distance-1
//    prefetch); compiler emits fine-grained vmcnt(N), AITER-style.
//    128x128 block, 4 waves 2x2, each wave 64x64 = 4x4 frags of 16x16x32.
// ---------------------------------------------------------------------------
__global__ __launch_bounds__(256, 3) void gemm_ff(
    const bf16* __restrict__ A, const bf16* __restrict__ Bm,
    bf16* __restrict__ C) {
  const int tid  = threadIdx.x;
  const int wave = tid >> 6;
  const int lane = tid & 63;
  const int m0 = blockIdx.x * 128;
  const int nt = blockIdx.y;

  const int wm = (wave >> 1) * 64;   // wave row origin in tile
  const int wn = (wave & 1) * 64;    // wave col origin in tile
  const int lr = lane & 15;
  const int qd = lane >> 4;

  // Fragment base pointers (bf16-element offsets):
  //   A chunk (mt, kk):      elem = mt*32768 + kk*512 + lane*8,  mt = (m0+wm)/16 + mi
  //   B chunk (nt, kk, f):   elem = nt*262144 + kk*4096 + f*512 + lane*8, f = (wave&1)*4 + ni
  const bf16* Ap = A + (size_t)((m0 + wm) >> 4) * 32768 + lane * 8;
  const bf16* Bp = Bm + (size_t)nt * 262144 + (size_t)(wave & 1) * 2048 + lane * 8;

  floatx4 acc[4][4] = {};
  bf16x8 a0[4], b0[4], a1[4], b1[4];

#pragma unroll
  for (int i = 0; i < 4; ++i) {        // preload kk = 0
    a0[i] = *(const bf16x8*)(Ap + i * 32768);
    b0[i] = *(const bf16x8*)(Bp + i * 512);
  }

  for (int kk = 0; kk < 64; kk += 2) {
#pragma unroll
    for (int i = 0; i < 4; ++i) {      // prefetch kk+1
      a1[i] = *(const bf16x8*)(Ap + i * 32768 + (kk + 1) * 512);
      b1[i] = *(const bf16x8*)(Bp + (size_t)(kk + 1) * 4096 + i * 512);
    }
#pragma unroll
    for (int mi = 0; mi < 4; ++mi)     // compute kk
#pragma unroll
      for (int ni = 0; ni < 4; ++ni)
        acc[mi][ni] = __builtin_amdgcn_mfma_f32_16x16x32_bf16(
            a0[mi], b0[ni], acc[mi][ni], 0, 0, 0);
    if (kk + 2 < 64) {
#pragma unroll
      for (int i = 0; i < 4; ++i) {    // prefetch kk+2
        a0[i] = *(const bf16x8*)(Ap + i * 32768 + (kk + 2) * 512);
        b0[i] = *(const bf16x8*)(Bp + (size_t)(kk + 2) * 4096 + i * 512);
      }
    }
#pragma unroll
    for (int mi = 0; mi < 4; ++mi)     // compute kk+1
#pragma unroll
      for (int ni = 0; ni < 4; ++ni)
        acc[mi][ni] = __builtin_amdgcn_mfma_f32_16x16x32_bf16(
            a1[mi], b1[ni], acc[mi][ni], 0, 0, 0);
  }

  // Store: C/D layout col = lane&15, row = (lane>>4)*4 + reg. bf16 store.
#pragma unroll
  for (int mi = 0; mi < 4; ++mi)
#pragma unroll
    for (int ni = 0; ni < 4; ++ni) {
      size_t base = (size_t)(m0 + wm + mi * 16 + qd * 4) * NG
                    + ((size_t)nt * 128 + wn + ni * 16 + lr);
#pragma unroll
      for (int r = 0; r < 4; ++r)
        C[base + (size_t)r * NG] = (bf16)acc[mi][ni][r];
    }
}

// ---------------------------------------------------------------------------
// 3. Fused epilogue: gates + inner MLP + cell update (reads bf16 G)
// ---------------------------------------------------------------------------
__global__ __launch_bounds__(256) void epilogue(
    const bf16* __restrict__ G, const float* __restrict__ c_prev,
    const float* __restrict__ bg, const float* __restrict__ bc,
    const float* __restrict__ W1, const float* __restrict__ b1,
    const float* __restrict__ W2, const float* __restrict__ b2,
    float* __restrict__ h_next, float* __restrict__ c_next) {
  int idx = blockIdx.x * 256 + threadIdx.x;   // one per (b,h)
  int b = idx >> 10;
  int h = idx & (HH - 1);
  const bf16* Gr = G + (size_t)b * NG;

  float gi = (float)Gr[h]          + bg[h];
  float gf = (float)Gr[HH + h]     + bg[HH + h];
  float go = (float)Gr[2 * HH + h] + bg[2 * HH + h];
  float p0 = (float)Gr[3 * HH + 2 * h]     + bc[2 * h];
  float p1 = (float)Gr[3 * HH + 2 * h + 1] + bc[2 * h + 1];

  float g = b2[0];
#pragma unroll
  for (int k = 0; k < KH; ++k) {
    float hv = fmaf(p0, W1[2 * k], fmaf(p1, W1[2 * k + 1], b1[k]));
    hv = fmaxf(hv, 0.0f);
    g = fmaf(hv, W2[k], g);
  }

  float si = 1.0f / (1.0f + __expf(-gi));
  float sf = 1.0f / (1.0f + __expf(-gf));
  float so = 1.0f / (1.0f + __expf(-go));

  float cn = sf * c_prev[idx] + si * g;
  float hn = so * tanhf(cn);
  h_next[idx] = hn;
  c_next[idx] = cn;
}

// ---------------------------------------------------------------------------
extern "C" void kernel_launch(void* const* d_in, const int* in_sizes, int n_in,
                              void* d_out, int out_size, void* d_ws, size_t ws_size,
                              hipStream_t stream) {
  const float* x      = (const float*)d_in[0];
  const float* h_prev = (const float*)d_in[1];
  const float* c_prev = (const float*)d_in[2];
  const float* Wg     = (const float*)d_in[3];
  const float* bg     = (const float*)d_in[4];
  const float* Wc     = (const float*)d_in[5];
  const float* bc     = (const float*)d_in[6];
  const float* W1     = (const float*)d_in[7];
  const float* b1     = (const float*)d_in[8];
  const float* W2     = (const float*)d_in[9];
  const float* b2     = (const float*)d_in[10];
  float* out = (float*)d_out;

  // workspace layout
  char* ws = (char*)d_ws;
  bf16* Ab = (bf16*)ws;                                      // 16 MB
  bf16* Wb = (bf16*)(ws + (size_t)BB * KIN * 2);             // 20 MB
  bf16* G  = (bf16*)(ws + (size_t)BB * KIN * 2
                        + (size_t)NG * KIN * 2);             // 40 MB

  // 1. prep (concat + casts + BOTH fragment shuffles, one kernel)
  prep<<<(NA8 + NW8 + 255) / 256, 256, 0, stream>>>(x, h_prev, Wg, Wc, Ab, Wb);

  // 2. GEMM (no LDS, no barriers)
  dim3 grid(BB / 128, NG / 128);
  gemm_ff<<<grid, 256, 0, stream>>>(Ab, Wb, G);

  // 3. epilogue
  epilogue<<<(BB * HH) / 256, 256, 0, stream>>>(
      G, c_prev, bg, bc, W1, b1, W2, b2, out, out + (size_t)BB * HH);
}

// Round 8
// 253.876 us; speedup vs baseline: 1.0979x; 1.0979x over previous
//
#include <hip/hip_runtime.h>
#include <hip/hip_bf16.h>

// Problem constants
#define BB   4096
#define INW  1024
#define HH   1024
#define KIN  2048      // IN + H
#define NG   5120      // 3H + 2H
#define KH   32        // inner hidden

typedef __bf16 bf16;
typedef __bf16 bf16x4 __attribute__((ext_vector_type(4)));
typedef __bf16 bf16x8 __attribute__((ext_vector_type(8)));
typedef float  floatx4 __attribute__((ext_vector_type(4)));

#define GLD16(gp, lp)                                                          \
  __builtin_amdgcn_global_load_lds(                                            \
      (__attribute__((address_space(1))) const void*)(gp),                     \
      (__attribute__((address_space(3))) void*)(lp), 16, 0, 0)

// ---------------------------------------------------------------------------
// 1. prep: concat+cast x|h_prev -> comb bf16 (flat), and shuffle-cast Wg,Wc
//    -> Wb in MFMA B-fragment order. 16B chunk o = [nt][kk][f][lane] holds
//    B[n = nt*128 + f*16 + (lane&15)][k = kk*32 + (lane>>4)*8 .. +7], so the
//    GEMM's B-fragment load is base + lane*16 — perfectly coalesced.
// ---------------------------------------------------------------------------
#define NC4  (BB * KIN / 4)        // float4 groups for comb      (2,097,152)
#define NW8  (NG * KIN / 8)        // 16B output chunks for Wb    (1,310,720)

__global__ __launch_bounds__(256) void prep(
    const float* __restrict__ x, const float* __restrict__ h,
    const float* __restrict__ Wg, const float* __restrict__ Wc,
    bf16* __restrict__ comb, bf16* __restrict__ Wb) {
  int i = blockIdx.x * 256 + threadIdx.x;
  if (i < NC4) {                       // ---- comb: concat + cast ----
    int e = i * 4;
    int b = e >> 11;          // / KIN
    int c = e & (KIN - 1);
    const float* src = (c < INW) ? (x + (size_t)b * INW + c)
                                 : (h + (size_t)b * HH + (c - INW));
    float4 v = *(const float4*)src;
    bf16x4 o4;
    o4[0] = (bf16)v.x; o4[1] = (bf16)v.y; o4[2] = (bf16)v.z; o4[3] = (bf16)v.w;
    *(bf16x4*)(comb + e) = o4;
  } else {                             // ---- Wb: fragment-order shuffle ----
    int o = i - NC4;
    if (o < NW8) {
      int lane = o & 63;
      int f    = (o >> 6) & 7;
      int kk   = (o >> 9) & 63;
      int nt   = o >> 15;
      int n = nt * 128 + f * 16 + (lane & 15);
      int k = kk * 32 + (lane >> 4) * 8;
      const float* src = (n < 3 * HH) ? (Wg + (size_t)n * KIN + k)
                                      : (Wc + (size_t)(n - 3 * HH) * KIN + k);
      float4 v0 = *(const float4*)src;
      float4 v1 = *(const float4*)(src + 4);
      bf16x8 ov;
      ov[0] = (bf16)v0.x; ov[1] = (bf16)v0.y; ov[2] = (bf16)v0.z; ov[3] = (bf16)v0.w;
      ov[4] = (bf16)v1.x; ov[5] = (bf16)v1.y; ov[6] = (bf16)v1.z; ov[7] = (bf16)v1.w;
      *(bf16x8*)(Wb + (size_t)o * 8) = ov;
    }
  }
}

// ---------------------------------------------------------------------------
// 2. GEMM: G[M,N] = A[M,K] * B[N,K]^T, B pre-shuffled to fragment order.
//    R8 = R6 champion + BK=128: two K-tiles per barrier pair. Barrier count
//    halves (16 vs 32) and MFMA per vmcnt(0) drain doubles (64 ~ 620 cyc),
//    amortizing the structural pre-barrier drain. LDS 32 KB single-buffered
//    (A only) — occupancy preserved, unlike m132's 64 KB dual-staged case.
//    A XOR swizzle generalized to 16 chunks/row: slot = c ^ (row&15);
//    bank check: 16 distinct slots per quad -> 2 lanes/bank -> free (m136).
// ---------------------------------------------------------------------------
__global__ __launch_bounds__(256, 3) void gemm_bt(
    const bf16* __restrict__ A, const bf16* __restrict__ Bm,
    bf16* __restrict__ C) {
  __shared__ bf16 As[128 * 128];   // 32 KB

  const int tid  = threadIdx.x;
  const int wave = tid >> 6;
  const int lane = tid & 63;
  const int m0 = blockIdx.x * 128;
  const int nt = blockIdx.y;

  const int wm = (wave >> 1) * 64;   // wave row origin in tile
  const int wn = (wave & 1) * 64;    // wave col origin in tile
  const int lr = lane & 15;          // row within 16x16 fragment
  const int qd = lane >> 4;          // k-chunk quad index (0..3)

  // B base for this wave/lane in fragment-order layout:
  // chunk = ((nt*64 + kk)*8 + f)*64 + lane, f = (wave&1)*4 + ni
  const bf16* Bq = Bm + (size_t)nt * 262144
                      + (size_t)((wave & 1) * 4) * 512 + (size_t)lane * 8;

  floatx4 acc[4][4] = {};

  for (int kt = 0; kt < KIN / 128; ++kt) {    // 16 iterations of BK=128
    // B fragment loads for the whole 128-k chunk — issued BEFORE the
    // barriers so the pre-barrier vmcnt(0) drain covers their latency.
    bf16x8 bfr[4][4];
#pragma unroll
    for (int ks = 0; ks < 4; ++ks)
#pragma unroll
      for (int ni = 0; ni < 4; ++ni)
        bfr[ks][ni] = *(const bf16x8*)(Bq + (size_t)(((kt * 4 + ks) * 8 + ni) << 9));

    __syncthreads();  // previous iter's LDS reads must finish before overwrite
#pragma unroll
    for (int j = 0; j < 8; ++j) {       // A: 2048 16B slots (128 rows x 16)
      int q   = j * 256 + tid;
      int row = q >> 4;
      int c   = (q & 15) ^ (row & 15);  // XOR swizzle
      GLD16(A + (size_t)(m0 + row) * KIN + kt * 128 + c * 8,
            As + (size_t)(j * 256 + wave * 64) * 8);
    }
    __syncthreads();

#pragma unroll
    for (int ks = 0; ks < 4; ++ks) {    // 4 k-steps of 32
      bf16x8 af[4];
#pragma unroll
      for (int mi = 0; mi < 4; ++mi) {
        int row  = wm + mi * 16 + lr;
        int slot = (ks * 4 + qd) ^ lr;  // row&15 == lr
        af[mi] = *(const bf16x8*)&As[(row << 7) + (slot << 3)];
      }
#pragma unroll
      for (int mi = 0; mi < 4; ++mi)
#pragma unroll
        for (int ni = 0; ni < 4; ++ni)
          acc[mi][ni] = __builtin_amdgcn_mfma_f32_16x16x32_bf16(
              af[mi], bfr[ks][ni], acc[mi][ni], 0, 0, 0);
    }
  }

  // Epilogue: C/D layout col = lane&15, row = (lane>>4)*4 + reg. bf16 store.
#pragma unroll
  for (int mi = 0; mi < 4; ++mi)
#pragma unroll
    for (int ni = 0; ni < 4; ++ni) {
      size_t base = (size_t)(m0 + wm + mi * 16 + qd * 4) * NG
                    + ((size_t)nt * 128 + wn + ni * 16 + lr);
#pragma unroll
      for (int r = 0; r < 4; ++r)
        C[base + (size_t)r * NG] = (bf16)acc[mi][ni][r];
    }
}

// ---------------------------------------------------------------------------
// 3. Fused epilogue: gates + inner MLP + cell update (reads bf16 G)
// ---------------------------------------------------------------------------
__global__ __launch_bounds__(256) void epilogue(
    const bf16* __restrict__ G, const float* __restrict__ c_prev,
    const float* __restrict__ bg, const float* __restrict__ bc,
    const float* __restrict__ W1, const float* __restrict__ b1,
    const float* __restrict__ W2, const float* __restrict__ b2,
    float* __restrict__ h_next, float* __restrict__ c_next) {
  int idx = blockIdx.x * 256 + threadIdx.x;   // one per (b,h)
  int b = idx >> 10;
  int h = idx & (HH - 1);
  const bf16* Gr = G + (size_t)b * NG;

  float gi = (float)Gr[h]          + bg[h];
  float gf = (float)Gr[HH + h]     + bg[HH + h];
  float go = (float)Gr[2 * HH + h] + bg[2 * HH + h];
  float p0 = (float)Gr[3 * HH + 2 * h]     + bc[2 * h];
  float p1 = (float)Gr[3 * HH + 2 * h + 1] + bc[2 * h + 1];

  float g = b2[0];
#pragma unroll
  for (int k = 0; k < KH; ++k) {
    float hv = fmaf(p0, W1[2 * k], fmaf(p1, W1[2 * k + 1], b1[k]));
    hv = fmaxf(hv, 0.0f);
    g = fmaf(hv, W2[k], g);
  }

  float si = 1.0f / (1.0f + __expf(-gi));
  float sf = 1.0f / (1.0f + __expf(-gf));
  float so = 1.0f / (1.0f + __expf(-go));

  float cn = sf * c_prev[idx] + si * g;
  float hn = so * tanhf(cn);
  h_next[idx] = hn;
  c_next[idx] = cn;
}

// ---------------------------------------------------------------------------
extern "C" void kernel_launch(void* const* d_in, const int* in_sizes, int n_in,
                              void* d_out, int out_size, void* d_ws, size_t ws_size,
                              hipStream_t stream) {
  const float* x      = (const float*)d_in[0];
  const float* h_prev = (const float*)d_in[1];
  const float* c_prev = (const float*)d_in[2];
  const float* Wg     = (const float*)d_in[3];
  const float* bg     = (const float*)d_in[4];
  const float* Wc     = (const float*)d_in[5];
  const float* bc     = (const float*)d_in[6];
  const float* W1     = (const float*)d_in[7];
  const float* b1     = (const float*)d_in[8];
  const float* W2     = (const float*)d_in[9];
  const float* b2     = (const float*)d_in[10];
  float* out = (float*)d_out;

  // workspace layout
  char* ws = (char*)d_ws;
  bf16* comb = (bf16*)ws;                                    // 16 MB
  bf16* Wb   = (bf16*)(ws + (size_t)BB * KIN * 2);           // 20 MB
  bf16* G    = (bf16*)(ws + (size_t)BB * KIN * 2
                          + (size_t)NG * KIN * 2);           // 40 MB

  // 1. prep (concat + casts + B fragment shuffle, one kernel)
  prep<<<(NC4 + NW8 + 255) / 256, 256, 0, stream>>>(x, h_prev, Wg, Wc, comb, Wb);

  // 2. GEMM
  dim3 grid(BB / 128, NG / 128);
  gemm_bt<<<grid, 256, 0, stream>>>(comb, Wb, G);

  // 3. epilogue
  epilogue<<<(BB * HH) / 256, 256, 0, stream>>>(
      G, c_prev, bg, bc, W1, b1, W2, b2, out, out + (size_t)BB * HH);
}